// Round 22
// baseline (233.025 us; speedup 1.0000x reference)
//
#include <hip/hip_runtime.h>
#include <hip/hip_bf16.h>

#define FEATS 1024
#define NH 16
#define HD 64
#define SEQ 2048
#define BATCH 2
#define MTOT (BATCH*SEQ)   // 4096
#define MLPH 4096
// log2(e)/sqrt(FEATS): folded into wq/bq so attn uses exp2f(s) directly
#define QSCALE 0.04508422277369218f

typedef __attribute__((ext_vector_type(8))) short bf16x8;   // 8 bf16 (4 VGPRs)
typedef __attribute__((ext_vector_type(4))) float f32x4;

static_assert(sizeof(bf16x8) == 16, "bf16x8 must be 16B");

__device__ __forceinline__ unsigned short f2bf(float f) {
    unsigned int u = __float_as_uint(f);
    unsigned int lsb = (u >> 16) & 1u;
    u += 0x7fffu + lsb;              // round-to-nearest-even
    return (unsigned short)(u >> 16);
}
__device__ __forceinline__ float bf2f(unsigned short u) {
    return __uint_as_float((unsigned)u << 16);
}

// async global->LDS, 16B per lane. Dest must be wave-uniform base + lane*16.
#define ASYNC16(GP, LP) __builtin_amdgcn_global_load_lds( \
    (const __attribute__((address_space(1))) void*)(GP),  \
    (__attribute__((address_space(3))) void*)(LP), 16, 0, 0)

#define WAIT_VM(N) asm volatile("s_waitcnt vmcnt(" #N ")" ::: "memory")

// ---------------------------------------------------------------- converts
__global__ __launch_bounds__(256) void cvt_all_kernel(
    const float* __restrict__ wq, const float* __restrict__ wk,
    const float* __restrict__ wv, const float* __restrict__ wo,
    const float* __restrict__ w1, const float* __restrict__ w2,
    unsigned short* __restrict__ dst) {
    const size_t i = ((size_t)blockIdx.x * 256 + threadIdx.x) * 4;
    const size_t MB = (size_t)1024 * 1024;
    const float* s;
    size_t off;
    float sc = 1.0f;
    if (i < MB)            { s = wq; off = i;          sc = QSCALE; }
    else if (i < 2 * MB)   { s = wk; off = i - MB; }
    else if (i < 3 * MB)   { s = wv; off = i - 2 * MB; }
    else if (i < 4 * MB)   { s = wo; off = i - 3 * MB; }
    else if (i < 8 * MB)   { s = w1; off = i - 4 * MB; }
    else                   { s = w2; off = i - 8 * MB; }
    float4 v = *(const float4*)(s + off);
    ushort4 o;
    o.x = f2bf(v.x * sc); o.y = f2bf(v.y * sc);
    o.z = f2bf(v.z * sc); o.w = f2bf(v.w * sc);
    *(ushort4*)(dst + i) = o;
}

__global__ __launch_bounds__(256) void concat3_kernel(const float* __restrict__ a,
                                                      const float* __restrict__ b,
                                                      const float* __restrict__ c,
                                                      float* __restrict__ o) {
    int i = blockIdx.x * 256 + threadIdx.x;   // 3072 total
    float v = (i < 1024) ? a[i] * QSCALE : ((i < 2048) ? b[i - 1024] : c[i - 2048]);
    o[i] = v;
}

// ---------------------------------------------------------------- layernorm
// INBF16: input rows are bf16 (out1b); else fp32.
template <bool INBF16>
__global__ __launch_bounds__(256) void ln_kernel(const void* __restrict__ xin,
                                                 const float* __restrict__ g,
                                                 const float* __restrict__ bta,
                                                 unsigned short* __restrict__ h) {
    __shared__ float red[8];
    const int row = blockIdx.x;
    const int t = threadIdx.x;
    float4 v;
    if (INBF16) {
        const unsigned short* xr = (const unsigned short*)xin + (size_t)row * FEATS;
        ushort4 u = ((const ushort4*)xr)[t];
        v.x = bf2f(u.x); v.y = bf2f(u.y); v.z = bf2f(u.z); v.w = bf2f(u.w);
    } else {
        const float* xr = (const float*)xin + (size_t)row * FEATS;
        v = ((const float4*)xr)[t];
    }
    float s  = v.x + v.y + v.z + v.w;
    float ss = v.x * v.x + v.y * v.y + v.z * v.z + v.w * v.w;
#pragma unroll
    for (int off = 1; off < 64; off <<= 1) {
        s  += __shfl_xor(s, off);
        ss += __shfl_xor(ss, off);
    }
    const int w = t >> 6;
    if ((t & 63) == 0) { red[w] = s; red[4 + w] = ss; }
    __syncthreads();
    s  = red[0] + red[1] + red[2] + red[3];
    ss = red[4] + red[5] + red[6] + red[7];
    const float mu  = s * (1.f / FEATS);
    const float var = ss * (1.f / FEATS) - mu * mu;
    const float rs  = rsqrtf(var + 1e-5f);
    float4 gv = ((const float4*)g)[t];
    float4 bv = ((const float4*)bta)[t];
    ushort4 ov;
    ov.x = f2bf((v.x - mu) * rs * gv.x + bv.x);
    ov.y = f2bf((v.y - mu) * rs * gv.y + bv.y);
    ov.z = f2bf((v.z - mu) * rs * gv.z + bv.z);
    ov.w = f2bf((v.w - mu) * rs * gv.w + bv.w);
    ((ushort4*)h)[(size_t)row * (FEATS / 4) + t] = ov;
}

// ---------------------------------------------------------------- GEMM
// C[M,N] = epilogue(A[M,K] @ W[N,K]^T + bias); 128x128 tile, BK=32.
// DEPTH LDS buffers, DEPTH-1 tiles in flight, counted vmcnt.
// DEPTH=2 (32KB, 4 blocks/CU) / DEPTH=3 (48KB, 3/CU) / DEPTH=4 (64KB, 2/CU).
// ADDF32/ADDBF16: residual addend dtype. T2-lite XOR swizzle both-sides.
// VTRANS (QKV only): tiles with col>=2048 are the V projection - written
// directly to vt[bh][d][P(seq)] (PV key-slot permutation P baked in).
template <int DEPTH, bool RELU, bool ADDF32, bool ADDBF16, bool OUTBF16, bool VTRANS>
__global__ __launch_bounds__(256, (DEPTH == 2 ? 4 : DEPTH == 3 ? 3 : 2))
void gemm_kernel(const unsigned short* __restrict__ A,
                 const unsigned short* __restrict__ W,
                 const float* __restrict__ bias,
                 const void* __restrict__ addend,
                 void* __restrict__ outp,
                 unsigned short* __restrict__ vtp,
                 int M, int N, int K, int gx) {
    __shared__ unsigned short lds[DEPTH][2][128 * 32];  // [buf][A/B][row*32+col]

    const int t = threadIdx.x;
    const int w = t >> 6, lane = t & 63;
    const int wr = w >> 1, wc = w & 1;
    const int li = lane & 15, lj = lane >> 4;

    const int nwg = gridDim.x;
    const int cpx = nwg >> 3;
    const int wg = blockIdx.x;
    const int swz = (wg & 7) * cpx + (wg >> 3);
    const int mb = (swz / gx) * 128, nb = (swz % gx) * 128;

    // staging: row srow = lane>>2; global slot pre-swizzled by row&3
    const int srow = lane >> 2;
    const int scg = ((lane & 3) ^ (srow & 3)) * 8;
    const unsigned short* gA = A + (size_t)(mb + w * 16 + srow) * K + scg;
    const unsigned short* gB = W + (size_t)(nb + w * 16 + srow) * K + scg;
    const size_t half = (size_t)64 * K;
    const int lbase = w * 512 + lane * 8;

    // fragment read slot: lj ^ (row&3), row&3 == li&3 for all frag rows
    const int rsw = (lj ^ (li & 3)) * 8;

    const int nt = K >> 5;

#define STAGE(BUF, K0)                                             \
    do {                                                           \
        unsigned short* la_ = &lds[BUF][0][lbase];                 \
        unsigned short* lb_ = &lds[BUF][1][lbase];                 \
        ASYNC16(gA + (K0), la_);                                   \
        ASYNC16(gA + half + (K0), la_ + 2048);                     \
        ASYNC16(gB + (K0), lb_);                                   \
        ASYNC16(gB + half + (K0), lb_ + 2048);                     \
    } while (0)

    // prologue: stage DEPTH-1 tiles, wait for tile 0 only
#pragma unroll
    for (int j = 0; j < DEPTH - 1; ++j)
        STAGE(j, j * 32);
    if constexpr (DEPTH == 2)      WAIT_VM(0);
    else if constexpr (DEPTH == 3) WAIT_VM(4);
    else                           WAIT_VM(8);
    __builtin_amdgcn_s_barrier();

    f32x4 acc[4][4] = {};

    for (int i = 0; i < nt; ++i) {
        const int cur = i % DEPTH;
        const unsigned short* Al = &lds[cur][0][0];
        const unsigned short* Bl = &lds[cur][1][0];

        bf16x8 af[4], bfr[4];
#pragma unroll
        for (int m = 0; m < 4; m++)
            af[m] = *(const bf16x8*)(Al + (wr * 64 + m * 16 + li) * 32 + rsw);
#pragma unroll
        for (int n = 0; n < 4; n++)
            bfr[n] = *(const bf16x8*)(Bl + (wc * 64 + n * 16 + li) * 32 + rsw);

        const int pft = i + DEPTH - 1;
        if (pft < nt) STAGE(pft % DEPTH, pft * 32);

#pragma unroll
        for (int m = 0; m < 4; m++)
#pragma unroll
            for (int n = 0; n < 4; n++)
                acc[m][n] = __builtin_amdgcn_mfma_f32_16x16x32_bf16(af[m], bfr[n], acc[m][n], 0, 0, 0);

        if (i + 1 < nt) {
            const int avail = (nt - 2) - i;
            const int rem = avail < (DEPTH - 2) ? avail : (DEPTH - 2);
            if (rem >= DEPTH - 2) {
                if constexpr (DEPTH == 2)      WAIT_VM(0);
                else if constexpr (DEPTH == 3) WAIT_VM(4);
                else                           WAIT_VM(8);
            }
            else if (rem == 1) WAIT_VM(4);
            else               WAIT_VM(0);
            __builtin_amdgcn_s_barrier();
        }
    }
#undef STAGE

#pragma unroll
    for (int m = 0; m < 4; m++) {
#pragma unroll
        for (int n = 0; n < 4; n++) {
            const int col = nb + wc * 64 + n * 16 + li;
            const float bv = bias[col];
            if (VTRANS && col >= 2048) {
                // V projection: write transposed+permuted, 1 ushort4/frag
                const int d2 = col - 2048;
                const int h2 = d2 >> 6, dd = d2 & 63;
                const int rowb = mb + wr * 64 + m * 16 + lj * 4;
                const int bb = rowb >> 11;            // / SEQ
                const int s0 = rowb & (SEQ - 1);
                const int pos = (s0 & ~31) | (((s0 >> 2) & 3) << 3) | (((s0 >> 4) & 1) << 2);
                ushort4 vv;
                vv.x = f2bf(acc[m][n][0] + bv);
                vv.y = f2bf(acc[m][n][1] + bv);
                vv.z = f2bf(acc[m][n][2] + bv);
                vv.w = f2bf(acc[m][n][3] + bv);
                *(ushort4*)(vtp + ((size_t)(bb * NH + h2) * HD + dd) * SEQ + pos) = vv;
                continue;
            }
#pragma unroll
            for (int r = 0; r < 4; r++) {
                const int row = mb + wr * 64 + m * 16 + lj * 4 + r;
                float v = acc[m][n][r] + bv;
                if (RELU) v = fmaxf(v, 0.f);
                if (ADDF32)
                    v += ((const float*)addend)[(size_t)row * N + col];
                if (ADDBF16)
                    v += bf2f(((const unsigned short*)addend)[(size_t)row * N + col]);
                if (OUTBF16)
                    ((unsigned short*)outp)[(size_t)row * N + col] = f2bf(v);
                else
                    ((float*)outp)[(size_t)row * N + col] = v;
            }
        }
    }
}

// ---------------------------------------------------------------- attention
// 256 thr (4 waves x 32 q-rows), KV tile 64, gload_lds staging with XOR
// slot swizzle. SOFTWARE PIPELINE (T15): 4 LDS buffers (64KB - free, grid
// caps residency at 2 blocks/CU), counted vmcnt(4) keeps 2 tiles in
// flight; QK of tile i+1 (independent MFMAs) issues UNDER exp/cvt/PV of
// tile i (VALU), breaking the QK->exp->PV serial chain. S regs
// double-buffered (sA/sB, manual unroll-by-2; rule #20). Fat waves +
// pre-permuted vt + ones-MFMA denominators + swapped QK^T.
__global__ __launch_bounds__(256, 2)
void attn_kernel(const unsigned short* __restrict__ qkv,
                 const unsigned short* __restrict__ vt,
                 unsigned short* __restrict__ out) {
    __shared__ unsigned short Kl[4][64 * 64];    // [key][d]  (swizzled slots)
    __shared__ unsigned short Vtl[4][64 * 64];   // [d][key]  (pre-permuted vt)

    const int bh = blockIdx.x;
    const int b = bh >> 4, h = bh & 15;
    const int q0 = blockIdx.y * 128;
    const int t = threadIdx.x, w = t >> 6, lane = t & 63;
    const int li = lane & 15, lj = lane >> 4;
    const int e7 = li & 7;

    const size_t rstr = 3 * FEATS;
    const unsigned short* qkvb = qkv + (size_t)(b * SEQ) * rstr;
    const unsigned short* ksrc = qkvb + FEATS + h * HD;
    const unsigned short* vsrc = vt + (size_t)bh * HD * SEQ;

    // Q fragments: two 16-row halves per wave
    bf16x8 aq[2][2];
#pragma unroll
    for (int hh = 0; hh < 2; hh++)
#pragma unroll
        for (int kk = 0; kk < 2; kk++)
            aq[hh][kk] = *(const bf16x8*)(qkvb +
                (size_t)(q0 + w * 32 + hh * 16 + li) * rstr + h * HD + kk * 32 + lj * 8);

    f32x4 o[2][4] = {};
    f32x4 oS[2] = {};   // denominators (ones-MFMA accumulator)

    const short onebf = (short)0x3F80;   // bf16 1.0
    const bf16x8 ones = {onebf, onebf, onebf, onebf, onebf, onebf, onebf, onebf};

    // staging: thread t -> row t>>3, slot (t&7)^(row&7); round 2 adds 32 rows
    const int srow = t >> 3;
    const int sslot = (t & 7) ^ (srow & 7);
    const unsigned short* kg = ksrc + (size_t)srow * rstr + sslot * 8;
    const unsigned short* vg = vsrc + (size_t)srow * SEQ + sslot * 8;
    const int ldst = t * 8;   // shorts; round 2 at +2048

#define STAGEA(BUF, KV0)                                              \
    do {                                                              \
        ASYNC16(kg + (size_t)(KV0) * rstr, &Kl[BUF][ldst]);           \
        ASYNC16(kg + (size_t)((KV0) + 32) * rstr, &Kl[BUF][ldst + 2048]); \
        ASYNC16(vg + (KV0), &Vtl[BUF][ldst]);                         \
        ASYNC16(vg + 32 * SEQ + (KV0), &Vtl[BUF][ldst + 2048]);       \
    } while (0)

    const int nt = SEQ / 64;   // 32 (even)

    STAGEA(0, 0);
    STAGEA(1, 64);
    STAGEA(2, 128);
    WAIT_VM(8);                 // tiles 0,1 landed; tile 2 in flight
    __builtin_amdgcn_s_barrier();

    f32x4 sA[2][4], sB[2][4];

    // QK of a tile: lane holds S[q=li][key = n*16 + lj*4 + r]
    auto qk_tile = [&](const unsigned short* Kc, f32x4 (&s)[2][4]) {
        __builtin_amdgcn_s_setprio(1);
#pragma unroll
        for (int n = 0; n < 4; n++) {
            const int rb = (n * 16 + li) * 64;
            bf16x8 k0 = *(const bf16x8*)(Kc + rb + ((lj ^ e7) * 8));
            bf16x8 k1 = *(const bf16x8*)(Kc + rb + (((lj + 4) ^ e7) * 8));
#pragma unroll
            for (int hh = 0; hh < 2; hh++) {
                f32x4 acc = {};
                acc = __builtin_amdgcn_mfma_f32_16x16x32_bf16(k0, aq[hh][0], acc, 0, 0, 0);
                acc = __builtin_amdgcn_mfma_f32_16x16x32_bf16(k1, aq[hh][1], acc, 0, 0, 0);
                s[hh][n] = acc;
            }
        }
        __builtin_amdgcn_s_setprio(0);
    };

    qk_tile(Kl[0], sA);   // tile 0's scores

    // one pipeline step: QK(i+1) into SNXT (indep MFMAs) || exp/PV(i) of SCUR
    auto body = [&](f32x4 (&SCUR)[2][4], f32x4 (&SNXT)[2][4], int i) {
        if (i + 3 < nt) STAGEA((i + 3) & 3, (i + 3) * 64);
        if (i + 1 < nt) qk_tile(Kl[(i + 1) & 3], SNXT);

        // ---- p = exp2(s) (pre-scaled); pack PV A-frags in-register ----
        bf16x8 A[2][2];
#pragma unroll
        for (int hh = 0; hh < 2; hh++)
#pragma unroll
            for (int kk = 0; kk < 2; kk++) {
                float p[8];
#pragma unroll
                for (int r = 0; r < 4; r++) {
                    p[r]     = exp2f(SCUR[hh][2 * kk][r]);
                    p[4 + r] = exp2f(SCUR[hh][2 * kk + 1][r]);
                }
                union { unsigned u[4]; bf16x8 v; } Au;
                asm("v_cvt_pk_bf16_f32 %0, %1, %2" : "=v"(Au.u[0]) : "v"(p[0]), "v"(p[1]));
                asm("v_cvt_pk_bf16_f32 %0, %1, %2" : "=v"(Au.u[1]) : "v"(p[2]), "v"(p[3]));
                asm("v_cvt_pk_bf16_f32 %0, %1, %2" : "=v"(Au.u[2]) : "v"(p[4]), "v"(p[5]));
                asm("v_cvt_pk_bf16_f32 %0, %1, %2" : "=v"(Au.u[3]) : "v"(p[6]), "v"(p[7]));
                A[hh][kk] = Au.v;
            }

        // ---- denominators: oS += A * ones (register B-operand) ----
#pragma unroll
        for (int hh = 0; hh < 2; hh++)
#pragma unroll
            for (int kk = 0; kk < 2; kk++)
                oS[hh] = __builtin_amdgcn_mfma_f32_16x16x32_bf16(A[hh][kk], ones, oS[hh], 0, 0, 0);

        // ---- O += P V (Vtl pre-permuted; swizzled b128 frags, shared) ----
        const unsigned short* Vc = Vtl[i & 3];
        __builtin_amdgcn_s_setprio(1);
#pragma unroll
        for (int n = 0; n < 4; n++) {
            const int rb = (n * 16 + li) * 64;
            bf16x8 bv0 = *(const bf16x8*)(Vc + rb + ((lj ^ e7) * 8));
            bf16x8 bv1 = *(const bf16x8*)(Vc + rb + (((lj + 4) ^ e7) * 8));
            o[0][n] = __builtin_amdgcn_mfma_f32_16x16x32_bf16(A[0][0], bv0, o[0][n], 0, 0, 0);
            o[1][n] = __builtin_amdgcn_mfma_f32_16x16x32_bf16(A[1][0], bv0, o[1][n], 0, 0, 0);
            o[0][n] = __builtin_amdgcn_mfma_f32_16x16x32_bf16(A[0][1], bv1, o[0][n], 0, 0, 0);
            o[1][n] = __builtin_amdgcn_mfma_f32_16x16x32_bf16(A[1][1], bv1, o[1][n], 0, 0, 0);
        }
        __builtin_amdgcn_s_setprio(0);

        if (i + 1 < nt) {
            // ensure tile i+2 landed for next iter's QK; keep i+3 in flight
            if (i + 3 < nt) WAIT_VM(4);
            else            WAIT_VM(0);
            __builtin_amdgcn_s_barrier();
        }
    };

    for (int i = 0; i < nt; i += 2) {
        body(sA, sB, i);
        body(sB, sA, i + 1);
    }
#undef STAGEA

    // epilogue: oS[hh][r] is the full denominator for q-row hh*16 + lj*4 + r
    unsigned short* ob = out + (size_t)(b * SEQ + q0 + w * 32) * FEATS + h * HD;
#pragma unroll
    for (int hh = 0; hh < 2; hh++)
#pragma unroll
        for (int r = 0; r < 4; r++) {
            const float inv = 1.f / oS[hh][r];
#pragma unroll
            for (int n = 0; n < 4; n++)
                ob[(size_t)(hh * 16 + lj * 4 + r) * FEATS + n * 16 + li] =
                    f2bf(o[hh][n][r] * inv);
        }
}

// ---------------------------------------------------------------- launch
extern "C" void kernel_launch(void* const* d_in, const int* in_sizes, int n_in,
                              void* d_out, int out_size, void* d_ws, size_t ws_size,
                              hipStream_t stream) {
    const float* x     = (const float*)d_in[0];
    const float* ln1_g = (const float*)d_in[1];
    const float* ln1_b = (const float*)d_in[2];
    const float* wq    = (const float*)d_in[3];
    const float* bq    = (const float*)d_in[4];
    const float* wk    = (const float*)d_in[5];
    const float* bk    = (const float*)d_in[6];
    const float* wv    = (const float*)d_in[7];
    const float* bvv   = (const float*)d_in[8];
    const float* wo    = (const float*)d_in[9];
    const float* bo    = (const float*)d_in[10];
    const float* ln2_g = (const float*)d_in[11];
    const float* ln2_b = (const float*)d_in[12];
    const float* w1    = (const float*)d_in[13];
    const float* b1    = (const float*)d_in[14];
    const float* w2    = (const float*)d_in[15];
    const float* b2    = (const float*)d_in[16];

    // ---- workspace layout (offsets in MB, 80 MB high-water) ----
    // [0,24) weights | [24,48) qkvb (Q,K only; V never written)
    // [48,56) hb | [24,56) a1 (after attn) | [56,64) attn_o/h2
    // [64,72) out1b | [72,80) vtb (written by QKV gemm epilogue)
    constexpr size_t MBs = 512 * 1024;   // shorts per MB
    unsigned short* ws16   = (unsigned short*)d_ws;
    unsigned short* wqkv_b = ws16;
    unsigned short* wo_b   = ws16 + 6 * MBs;
    unsigned short* w1_b   = ws16 + 8 * MBs;
    unsigned short* w2_b   = ws16 + 16 * MBs;
    unsigned short* qkvb   = ws16 + 24 * MBs;             // 24MB
    unsigned short* hb     = ws16 + 48 * MBs;             // 8MB (LN1 out)
    unsigned short* a1     = ws16 + 24 * MBs;             // 32MB (qkvb+hb dead after attn)
    unsigned short* attn_o = ws16 + 56 * MBs;             // 8MB
    unsigned short* h2     = attn_o;                      // alias
    unsigned short* out1b  = ws16 + 64 * MBs;             // 8MB bf16
    unsigned short* vtb    = ws16 + 72 * MBs;             // 8MB
    float*          bqkv   = (float*)(ws16 + 80 * MBs);   // 12KB
    float*          outf   = (float*)d_out;

    dim3 blk(256);

    cvt_all_kernel<<<12288, blk, 0, stream>>>(wq, wk, wv, wo, w1, w2, wqkv_b);
    concat3_kernel<<<12, blk, 0, stream>>>(bq, bk, bvv, bqkv);

    ln_kernel<false><<<MTOT, blk, 0, stream>>>(x, ln1_g, ln1_b, hb);

    // fused QKV gemm + inline V-transpose: 768 blocks (3/CU)
    gemm_kernel<3, false, false, false, true, true><<<768, blk, 0, stream>>>(
        hb, wqkv_b, bqkv, nullptr, qkvb, vtb, MTOT, 3072, FEATS, 24);

    attn_kernel<<<dim3(BATCH * NH, SEQ / 128), blk, 0, stream>>>(qkvb, vtb, attn_o);

    // out proj + residual(x, fp32) -> bf16 out1b: 256 blocks, DEPTH=4
    gemm_kernel<4, false, true, false, true, false><<<256, blk, 0, stream>>>(
        attn_o, wo_b, bo, x, out1b, nullptr, MTOT, FEATS, FEATS, 8);

    ln_kernel<true><<<MTOT, blk, 0, stream>>>(out1b, ln2_g, ln2_b, h2);

    // MLP1: 1024 blocks -> DEPTH=2 (32KB LDS, 4 blocks/CU, zero tail)
    gemm_kernel<2, true, false, false, true, false><<<1024, blk, 0, stream>>>(
        h2, w1_b, b1, nullptr, a1, nullptr, MTOT, MLPH, FEATS, 32);

    // MLP2 + residual(out1b, bf16) -> fp32 d_out: 256 blocks, DEPTH=4
    gemm_kernel<4, true, false, true, false, false><<<256, blk, 0, stream>>>(
        a1, w2_b, b2, out1b, outf, nullptr, MTOT, FEATS, MLPH, 8);
}

// Round 23
// 222.956 us; speedup vs baseline: 1.0452x; 1.0452x over previous
//
#include <hip/hip_runtime.h>
#include <hip/hip_bf16.h>

#define FEATS 1024
#define NH 16
#define HD 64
#define SEQ 2048
#define BATCH 2
#define MTOT (BATCH*SEQ)   // 4096
#define MLPH 4096
// log2(e)/sqrt(FEATS): folded into wq/bq so attn uses exp2f(s) directly
#define QSCALE 0.04508422277369218f

typedef __attribute__((ext_vector_type(8))) short bf16x8;   // 8 bf16 (4 VGPRs)
typedef __attribute__((ext_vector_type(4))) float f32x4;

static_assert(sizeof(bf16x8) == 16, "bf16x8 must be 16B");

__device__ __forceinline__ unsigned short f2bf(float f) {
    unsigned int u = __float_as_uint(f);
    unsigned int lsb = (u >> 16) & 1u;
    u += 0x7fffu + lsb;              // round-to-nearest-even
    return (unsigned short)(u >> 16);
}
__device__ __forceinline__ float bf2f(unsigned short u) {
    return __uint_as_float((unsigned)u << 16);
}

// async global->LDS, 16B per lane. Dest must be wave-uniform base + lane*16.
#define ASYNC16(GP, LP) __builtin_amdgcn_global_load_lds( \
    (const __attribute__((address_space(1))) void*)(GP),  \
    (__attribute__((address_space(3))) void*)(LP), 16, 0, 0)

#define WAIT_VM(N) asm volatile("s_waitcnt vmcnt(" #N ")" ::: "memory")

// ---------------------------------------------------------------- converts
__global__ __launch_bounds__(256) void cvt_all_kernel(
    const float* __restrict__ wq, const float* __restrict__ wk,
    const float* __restrict__ wv, const float* __restrict__ wo,
    const float* __restrict__ w1, const float* __restrict__ w2,
    unsigned short* __restrict__ dst) {
    const size_t i = ((size_t)blockIdx.x * 256 + threadIdx.x) * 4;
    const size_t MB = (size_t)1024 * 1024;
    const float* s;
    size_t off;
    float sc = 1.0f;
    if (i < MB)            { s = wq; off = i;          sc = QSCALE; }
    else if (i < 2 * MB)   { s = wk; off = i - MB; }
    else if (i < 3 * MB)   { s = wv; off = i - 2 * MB; }
    else if (i < 4 * MB)   { s = wo; off = i - 3 * MB; }
    else if (i < 8 * MB)   { s = w1; off = i - 4 * MB; }
    else                   { s = w2; off = i - 8 * MB; }
    float4 v = *(const float4*)(s + off);
    ushort4 o;
    o.x = f2bf(v.x * sc); o.y = f2bf(v.y * sc);
    o.z = f2bf(v.z * sc); o.w = f2bf(v.w * sc);
    *(ushort4*)(dst + i) = o;
}

__global__ __launch_bounds__(256) void concat3_kernel(const float* __restrict__ a,
                                                      const float* __restrict__ b,
                                                      const float* __restrict__ c,
                                                      float* __restrict__ o) {
    int i = blockIdx.x * 256 + threadIdx.x;   // 3072 total
    float v = (i < 1024) ? a[i] * QSCALE : ((i < 2048) ? b[i - 1024] : c[i - 2048]);
    o[i] = v;
}

// ---------------------------------------------------------------- layernorm
// INBF16: input rows are bf16 (out1b); else fp32.
template <bool INBF16>
__global__ __launch_bounds__(256) void ln_kernel(const void* __restrict__ xin,
                                                 const float* __restrict__ g,
                                                 const float* __restrict__ bta,
                                                 unsigned short* __restrict__ h) {
    __shared__ float red[8];
    const int row = blockIdx.x;
    const int t = threadIdx.x;
    float4 v;
    if (INBF16) {
        const unsigned short* xr = (const unsigned short*)xin + (size_t)row * FEATS;
        ushort4 u = ((const ushort4*)xr)[t];
        v.x = bf2f(u.x); v.y = bf2f(u.y); v.z = bf2f(u.z); v.w = bf2f(u.w);
    } else {
        const float* xr = (const float*)xin + (size_t)row * FEATS;
        v = ((const float4*)xr)[t];
    }
    float s  = v.x + v.y + v.z + v.w;
    float ss = v.x * v.x + v.y * v.y + v.z * v.z + v.w * v.w;
#pragma unroll
    for (int off = 1; off < 64; off <<= 1) {
        s  += __shfl_xor(s, off);
        ss += __shfl_xor(ss, off);
    }
    const int w = t >> 6;
    if ((t & 63) == 0) { red[w] = s; red[4 + w] = ss; }
    __syncthreads();
    s  = red[0] + red[1] + red[2] + red[3];
    ss = red[4] + red[5] + red[6] + red[7];
    const float mu  = s * (1.f / FEATS);
    const float var = ss * (1.f / FEATS) - mu * mu;
    const float rs  = rsqrtf(var + 1e-5f);
    float4 gv = ((const float4*)g)[t];
    float4 bv = ((const float4*)bta)[t];
    ushort4 ov;
    ov.x = f2bf((v.x - mu) * rs * gv.x + bv.x);
    ov.y = f2bf((v.y - mu) * rs * gv.y + bv.y);
    ov.z = f2bf((v.z - mu) * rs * gv.z + bv.z);
    ov.w = f2bf((v.w - mu) * rs * gv.w + bv.w);
    ((ushort4*)h)[(size_t)row * (FEATS / 4) + t] = ov;
}

// ---------------------------------------------------------------- GEMM
// C[M,N] = epilogue(A[M,K] @ W[N,K]^T + bias); 128x128 tile, BK=32.
// DEPTH LDS buffers, DEPTH-1 tiles in flight, counted vmcnt.
// DEPTH=2 (32KB, 4 blocks/CU) / DEPTH=3 (48KB, 3/CU) / DEPTH=4 (64KB, 2/CU).
// ADDF32/ADDBF16: residual addend dtype. T2-lite XOR swizzle both-sides.
// VTRANS (QKV only): tiles with col>=2048 are the V projection - written
// directly to vt[bh][d][P(seq)] (PV key-slot permutation P baked in).
template <int DEPTH, bool RELU, bool ADDF32, bool ADDBF16, bool OUTBF16, bool VTRANS>
__global__ __launch_bounds__(256, (DEPTH == 2 ? 4 : DEPTH == 3 ? 3 : 2))
void gemm_kernel(const unsigned short* __restrict__ A,
                 const unsigned short* __restrict__ W,
                 const float* __restrict__ bias,
                 const void* __restrict__ addend,
                 void* __restrict__ outp,
                 unsigned short* __restrict__ vtp,
                 int M, int N, int K, int gx) {
    __shared__ unsigned short lds[DEPTH][2][128 * 32];  // [buf][A/B][row*32+col]

    const int t = threadIdx.x;
    const int w = t >> 6, lane = t & 63;
    const int wr = w >> 1, wc = w & 1;
    const int li = lane & 15, lj = lane >> 4;

    const int nwg = gridDim.x;
    const int cpx = nwg >> 3;
    const int wg = blockIdx.x;
    const int swz = (wg & 7) * cpx + (wg >> 3);
    const int mb = (swz / gx) * 128, nb = (swz % gx) * 128;

    // staging: row srow = lane>>2; global slot pre-swizzled by row&3
    const int srow = lane >> 2;
    const int scg = ((lane & 3) ^ (srow & 3)) * 8;
    const unsigned short* gA = A + (size_t)(mb + w * 16 + srow) * K + scg;
    const unsigned short* gB = W + (size_t)(nb + w * 16 + srow) * K + scg;
    const size_t half = (size_t)64 * K;
    const int lbase = w * 512 + lane * 8;

    // fragment read slot: lj ^ (row&3), row&3 == li&3 for all frag rows
    const int rsw = (lj ^ (li & 3)) * 8;

    const int nt = K >> 5;

#define STAGE(BUF, K0)                                             \
    do {                                                           \
        unsigned short* la_ = &lds[BUF][0][lbase];                 \
        unsigned short* lb_ = &lds[BUF][1][lbase];                 \
        ASYNC16(gA + (K0), la_);                                   \
        ASYNC16(gA + half + (K0), la_ + 2048);                     \
        ASYNC16(gB + (K0), lb_);                                   \
        ASYNC16(gB + half + (K0), lb_ + 2048);                     \
    } while (0)

    // prologue: stage DEPTH-1 tiles, wait for tile 0 only
#pragma unroll
    for (int j = 0; j < DEPTH - 1; ++j)
        STAGE(j, j * 32);
    if constexpr (DEPTH == 2)      WAIT_VM(0);
    else if constexpr (DEPTH == 3) WAIT_VM(4);
    else                           WAIT_VM(8);
    __builtin_amdgcn_s_barrier();

    f32x4 acc[4][4] = {};

    for (int i = 0; i < nt; ++i) {
        const int cur = i % DEPTH;
        const unsigned short* Al = &lds[cur][0][0];
        const unsigned short* Bl = &lds[cur][1][0];

        bf16x8 af[4], bfr[4];
#pragma unroll
        for (int m = 0; m < 4; m++)
            af[m] = *(const bf16x8*)(Al + (wr * 64 + m * 16 + li) * 32 + rsw);
#pragma unroll
        for (int n = 0; n < 4; n++)
            bfr[n] = *(const bf16x8*)(Bl + (wc * 64 + n * 16 + li) * 32 + rsw);

        const int pft = i + DEPTH - 1;
        if (pft < nt) STAGE(pft % DEPTH, pft * 32);

#pragma unroll
        for (int m = 0; m < 4; m++)
#pragma unroll
            for (int n = 0; n < 4; n++)
                acc[m][n] = __builtin_amdgcn_mfma_f32_16x16x32_bf16(af[m], bfr[n], acc[m][n], 0, 0, 0);

        if (i + 1 < nt) {
            const int avail = (nt - 2) - i;
            const int rem = avail < (DEPTH - 2) ? avail : (DEPTH - 2);
            if (rem >= DEPTH - 2) {
                if constexpr (DEPTH == 2)      WAIT_VM(0);
                else if constexpr (DEPTH == 3) WAIT_VM(4);
                else                           WAIT_VM(8);
            }
            else if (rem == 1) WAIT_VM(4);
            else               WAIT_VM(0);
            __builtin_amdgcn_s_barrier();
        }
    }
#undef STAGE

#pragma unroll
    for (int m = 0; m < 4; m++) {
#pragma unroll
        for (int n = 0; n < 4; n++) {
            const int col = nb + wc * 64 + n * 16 + li;
            const float bv = bias[col];
            if (VTRANS && col >= 2048) {
                // V projection: write transposed+permuted, 1 ushort4/frag
                const int d2 = col - 2048;
                const int h2 = d2 >> 6, dd = d2 & 63;
                const int rowb = mb + wr * 64 + m * 16 + lj * 4;
                const int bb = rowb >> 11;            // / SEQ
                const int s0 = rowb & (SEQ - 1);
                const int pos = (s0 & ~31) | (((s0 >> 2) & 3) << 3) | (((s0 >> 4) & 1) << 2);
                ushort4 vv;
                vv.x = f2bf(acc[m][n][0] + bv);
                vv.y = f2bf(acc[m][n][1] + bv);
                vv.z = f2bf(acc[m][n][2] + bv);
                vv.w = f2bf(acc[m][n][3] + bv);
                *(ushort4*)(vtp + ((size_t)(bb * NH + h2) * HD + dd) * SEQ + pos) = vv;
                continue;
            }
#pragma unroll
            for (int r = 0; r < 4; r++) {
                const int row = mb + wr * 64 + m * 16 + lj * 4 + r;
                float v = acc[m][n][r] + bv;
                if (RELU) v = fmaxf(v, 0.f);
                if (ADDF32)
                    v += ((const float*)addend)[(size_t)row * N + col];
                if (ADDBF16)
                    v += bf2f(((const unsigned short*)addend)[(size_t)row * N + col]);
                if (OUTBF16)
                    ((unsigned short*)outp)[(size_t)row * N + col] = f2bf(v);
                else
                    ((float*)outp)[(size_t)row * N + col] = v;
            }
        }
    }
}

// ---------------------------------------------------------------- attention
// Best-known (62-63us): 256 thr (4 waves x 32 q-rows), KV tile 64. Staging
// via global_load_lds (no reg round-trip): LDS linear [64][64], both-sides
// XOR slot swizzle (source slot^(row&7), reads (lj^(li&7))) keeps frag
// reads conflict-free. DEPTH=2 loop: STAGE(next) -> compute(cur) ->
// vmcnt(0)+barrier. Fat waves + pre-permuted vt + ones-MFMA denominators
// + swapped QK^T (P lane-local).
__global__ __launch_bounds__(256, 4)
void attn_kernel(const unsigned short* __restrict__ qkv,
                 const unsigned short* __restrict__ vt,
                 unsigned short* __restrict__ out) {
    __shared__ unsigned short Kl[2][64 * 64];    // [key][d]  (swizzled slots)
    __shared__ unsigned short Vtl[2][64 * 64];   // [d][key]  (pre-permuted vt)

    const int bh = blockIdx.x;
    const int b = bh >> 4, h = bh & 15;
    const int q0 = blockIdx.y * 128;
    const int t = threadIdx.x, w = t >> 6, lane = t & 63;
    const int li = lane & 15, lj = lane >> 4;
    const int e7 = li & 7;

    const size_t rstr = 3 * FEATS;
    const unsigned short* qkvb = qkv + (size_t)(b * SEQ) * rstr;
    const unsigned short* ksrc = qkvb + FEATS + h * HD;
    const unsigned short* vsrc = vt + (size_t)bh * HD * SEQ;

    // Q fragments: two 16-row halves per wave
    bf16x8 aq[2][2];
#pragma unroll
    for (int hh = 0; hh < 2; hh++)
#pragma unroll
        for (int kk = 0; kk < 2; kk++)
            aq[hh][kk] = *(const bf16x8*)(qkvb +
                (size_t)(q0 + w * 32 + hh * 16 + li) * rstr + h * HD + kk * 32 + lj * 8);

    f32x4 o[2][4] = {};
    f32x4 oS[2] = {};   // denominators (ones-MFMA accumulator)

    const short onebf = (short)0x3F80;   // bf16 1.0
    const bf16x8 ones = {onebf, onebf, onebf, onebf, onebf, onebf, onebf, onebf};

    // staging: thread t -> row t>>3, slot (t&7)^(row&7); round 2 adds 32 rows
    const int srow = t >> 3;
    const int sslot = (t & 7) ^ (srow & 7);
    const unsigned short* kg = ksrc + (size_t)srow * rstr + sslot * 8;
    const unsigned short* vg = vsrc + (size_t)srow * SEQ + sslot * 8;
    const int ldst = t * 8;   // shorts; round 2 at +2048

#define STAGEA(BUF, KV0)                                              \
    do {                                                              \
        ASYNC16(kg + (size_t)(KV0) * rstr, &Kl[BUF][ldst]);           \
        ASYNC16(kg + (size_t)((KV0) + 32) * rstr, &Kl[BUF][ldst + 2048]); \
        ASYNC16(vg + (KV0), &Vtl[BUF][ldst]);                         \
        ASYNC16(vg + 32 * SEQ + (KV0), &Vtl[BUF][ldst + 2048]);       \
    } while (0)

    const int nt = SEQ / 64;   // 32

    STAGEA(0, 0);
    WAIT_VM(0);
    __builtin_amdgcn_s_barrier();

    int cur = 0;
    for (int i = 0; i < nt; ++i) {
        // prefetch next tile into the free buffer (lands during compute)
        if (i + 1 < nt) STAGEA(cur ^ 1, (i + 1) * 64);

        const unsigned short* Kc = Kl[cur];
        const unsigned short* Vc = Vtl[cur];

        // ---- S^T = K Q^T : both q-halves share each K fragment ----
        f32x4 s[2][4];
        __builtin_amdgcn_s_setprio(1);
#pragma unroll
        for (int n = 0; n < 4; n++) {
            const int rb = (n * 16 + li) * 64;
            bf16x8 k0 = *(const bf16x8*)(Kc + rb + ((lj ^ e7) * 8));
            bf16x8 k1 = *(const bf16x8*)(Kc + rb + (((lj + 4) ^ e7) * 8));
#pragma unroll
            for (int hh = 0; hh < 2; hh++) {
                f32x4 acc = {};
                acc = __builtin_amdgcn_mfma_f32_16x16x32_bf16(k0, aq[hh][0], acc, 0, 0, 0);
                acc = __builtin_amdgcn_mfma_f32_16x16x32_bf16(k1, aq[hh][1], acc, 0, 0, 0);
                s[hh][n] = acc;
            }
        }
        __builtin_amdgcn_s_setprio(0);

        // ---- p = exp2(s) (pre-scaled); pack PV A-frags in-register ----
        bf16x8 A[2][2];
#pragma unroll
        for (int hh = 0; hh < 2; hh++)
#pragma unroll
            for (int kk = 0; kk < 2; kk++) {
                float p[8];
#pragma unroll
                for (int r = 0; r < 4; r++) {
                    p[r]     = exp2f(s[hh][2 * kk][r]);
                    p[4 + r] = exp2f(s[hh][2 * kk + 1][r]);
                }
                union { unsigned u[4]; bf16x8 v; } Au;
                asm("v_cvt_pk_bf16_f32 %0, %1, %2" : "=v"(Au.u[0]) : "v"(p[0]), "v"(p[1]));
                asm("v_cvt_pk_bf16_f32 %0, %1, %2" : "=v"(Au.u[1]) : "v"(p[2]), "v"(p[3]));
                asm("v_cvt_pk_bf16_f32 %0, %1, %2" : "=v"(Au.u[2]) : "v"(p[4]), "v"(p[5]));
                asm("v_cvt_pk_bf16_f32 %0, %1, %2" : "=v"(Au.u[3]) : "v"(p[6]), "v"(p[7]));
                A[hh][kk] = Au.v;
            }

        // ---- denominators: oS += A * ones (register B-operand) ----
#pragma unroll
        for (int hh = 0; hh < 2; hh++)
#pragma unroll
            for (int kk = 0; kk < 2; kk++)
                oS[hh] = __builtin_amdgcn_mfma_f32_16x16x32_bf16(A[hh][kk], ones, oS[hh], 0, 0, 0);

        // ---- O += P V (Vtl pre-permuted; swizzled b128 frags, shared) ----
        __builtin_amdgcn_s_setprio(1);
#pragma unroll
        for (int n = 0; n < 4; n++) {
            const int rb = (n * 16 + li) * 64;
            bf16x8 bv0 = *(const bf16x8*)(Vc + rb + ((lj ^ e7) * 8));
            bf16x8 bv1 = *(const bf16x8*)(Vc + rb + (((lj + 4) ^ e7) * 8));
            o[0][n] = __builtin_amdgcn_mfma_f32_16x16x32_bf16(A[0][0], bv0, o[0][n], 0, 0, 0);
            o[1][n] = __builtin_amdgcn_mfma_f32_16x16x32_bf16(A[1][0], bv0, o[1][n], 0, 0, 0);
            o[0][n] = __builtin_amdgcn_mfma_f32_16x16x32_bf16(A[0][1], bv1, o[0][n], 0, 0, 0);
            o[1][n] = __builtin_amdgcn_mfma_f32_16x16x32_bf16(A[1][1], bv1, o[1][n], 0, 0, 0);
        }
        __builtin_amdgcn_s_setprio(0);

        if (i + 1 < nt) {
            WAIT_VM(0);
            __builtin_amdgcn_s_barrier();
        }
        cur ^= 1;
    }
#undef STAGEA

    // epilogue: oS[hh][r] is the full denominator for q-row hh*16 + lj*4 + r
    unsigned short* ob = out + (size_t)(b * SEQ + q0 + w * 32) * FEATS + h * HD;
#pragma unroll
    for (int hh = 0; hh < 2; hh++)
#pragma unroll
        for (int r = 0; r < 4; r++) {
            const float inv = 1.f / oS[hh][r];
#pragma unroll
            for (int n = 0; n < 4; n++)
                ob[(size_t)(hh * 16 + lj * 4 + r) * FEATS + n * 16 + li] =
                    f2bf(o[hh][n][r] * inv);
        }
}

// ---------------------------------------------------------------- launch
extern "C" void kernel_launch(void* const* d_in, const int* in_sizes, int n_in,
                              void* d_out, int out_size, void* d_ws, size_t ws_size,
                              hipStream_t stream) {
    const float* x     = (const float*)d_in[0];
    const float* ln1_g = (const float*)d_in[1];
    const float* ln1_b = (const float*)d_in[2];
    const float* wq    = (const float*)d_in[3];
    const float* bq    = (const float*)d_in[4];
    const float* wk    = (const float*)d_in[5];
    const float* bk    = (const float*)d_in[6];
    const float* wv    = (const float*)d_in[7];
    const float* bvv   = (const float*)d_in[8];
    const float* wo    = (const float*)d_in[9];
    const float* bo    = (const float*)d_in[10];
    const float* ln2_g = (const float*)d_in[11];
    const float* ln2_b = (const float*)d_in[12];
    const float* w1    = (const float*)d_in[13];
    const float* b1    = (const float*)d_in[14];
    const float* w2    = (const float*)d_in[15];
    const float* b2    = (const float*)d_in[16];

    // ---- workspace layout (offsets in MB, 80 MB high-water) ----
    // [0,24) weights | [24,48) qkvb (Q,K only; V never written)
    // [48,56) hb | [24,56) a1 (after attn) | [56,64) attn_o/h2
    // [64,72) out1b | [72,80) vtb (written by QKV gemm epilogue)
    constexpr size_t MBs = 512 * 1024;   // shorts per MB
    unsigned short* ws16   = (unsigned short*)d_ws;
    unsigned short* wqkv_b = ws16;
    unsigned short* wo_b   = ws16 + 6 * MBs;
    unsigned short* w1_b   = ws16 + 8 * MBs;
    unsigned short* w2_b   = ws16 + 16 * MBs;
    unsigned short* qkvb   = ws16 + 24 * MBs;             // 24MB
    unsigned short* hb     = ws16 + 48 * MBs;             // 8MB (LN1 out)
    unsigned short* a1     = ws16 + 24 * MBs;             // 32MB (qkvb+hb dead after attn)
    unsigned short* attn_o = ws16 + 56 * MBs;             // 8MB
    unsigned short* h2     = attn_o;                      // alias
    unsigned short* out1b  = ws16 + 64 * MBs;             // 8MB bf16
    unsigned short* vtb    = ws16 + 72 * MBs;             // 8MB
    float*          bqkv   = (float*)(ws16 + 80 * MBs);   // 12KB
    float*          outf   = (float*)d_out;

    dim3 blk(256);

    cvt_all_kernel<<<12288, blk, 0, stream>>>(wq, wk, wv, wo, w1, w2, wqkv_b);
    concat3_kernel<<<12, blk, 0, stream>>>(bq, bk, bvv, bqkv);

    ln_kernel<false><<<MTOT, blk, 0, stream>>>(x, ln1_g, ln1_b, hb);

    // fused QKV gemm + inline V-transpose: 768 blocks (3/CU)
    gemm_kernel<3, false, false, false, true, true><<<768, blk, 0, stream>>>(
        hb, wqkv_b, bqkv, nullptr, qkvb, vtb, MTOT, 3072, FEATS, 24);

    attn_kernel<<<dim3(BATCH * NH, SEQ / 128), blk, 0, stream>>>(qkvb, vtb, attn_o);

    // out proj + residual(x, fp32) -> bf16 out1b: 256 blocks, DEPTH=4
    gemm_kernel<4, false, true, false, true, false><<<256, blk, 0, stream>>>(
        attn_o, wo_b, bo, x, out1b, nullptr, MTOT, FEATS, FEATS, 8);

    ln_kernel<true><<<MTOT, blk, 0, stream>>>(out1b, ln2_g, ln2_b, h2);

    // MLP1: 1024 blocks -> DEPTH=2 (32KB LDS, 4 blocks/CU, zero tail)
    gemm_kernel<2, true, false, false, true, false><<<1024, blk, 0, stream>>>(
        h2, w1_b, b1, nullptr, a1, nullptr, MTOT, MLPH, FEATS, 32);

    // MLP2 + residual(out1b, bf16) -> fp32 d_out: 256 blocks, DEPTH=4
    gemm_kernel<4, true, false, true, false, false><<<256, blk, 0, stream>>>(
        a1, w2_b, b2, out1b, outf, nullptr, MTOT, FEATS, MLPH, 8);
}